// Round 1
// baseline (609.065 us; speedup 1.0000x reference)
//
#include <hip/hip_runtime.h>

// Problem constants (z: [4, 64, 32, 32, 32] f32, embedding: [1024, 64] f32)
#define CH     64
#define KC     1024
#define SP     32768              // 32*32*32
#define NBATCH 4
#define NTOK   (NBATCH * SP)      // 131072
#define MTOK   128                // tokens per block (32 per wave)
#define SZZ    68                 // zl row stride (floats): 272 B, 16B-aligned, 8-way-max banks
#define CAP    8                  // candidate slots per token (margin hits are ~1-3; overflow -> exact scan)
#define MARGIN 3.0f               // > 2*eps, eps = max |d_bf16 - d_fp32| (~0.9)

// d_out flat layout (all float32): z_q, loss, perplexity, indices, mean(dist)
#define OFF_ZQ   0
#define OFF_LOSS (NBATCH * CH * SP)      // 8388608
#define OFF_PERP (OFF_LOSS + 1)
#define OFF_IDX  (OFF_PERP + 1)          // 8388610
#define OFF_MEAN (OFF_IDX + NTOK)        // 8519682

// workspace layout (32-bit words)
// [0,1024)      int   hist
// [1024]        float sum_z2
// [1025]        float sum_e2
// [1026,1090)   float sum_zc[64]
// [1090,1154)   float sum_ec[64]
// [1154,2178)   float enorm[1024]
// [4096,20480)  ushort eb[1024*64]  (bf16 embedding table, 128 KB, L2-resident)

typedef __attribute__((ext_vector_type(8))) short  s16x8;   // 8 bf16 (4 VGPRs)
typedef __attribute__((ext_vector_type(4))) float  f32x4;

__device__ __forceinline__ unsigned short f2bf(float f) {   // RNE, deterministic
    unsigned int u = __float_as_uint(f);
    return (unsigned short)((u + 0x7fffu + ((u >> 16) & 1u)) >> 16);
}

// frozen exact fp32 distance (bitwise identical to prior rounds: stride-4
// fmaf chains ascending j, combine nrm - 2*((a0+a1)+(a2+a3)))
__device__ __forceinline__ float exact_dist(const float* zrow,
                                            const float* __restrict__ emb,
                                            const float* __restrict__ enl, int c) {
    const float4* er = (const float4*)(emb + (size_t)c * CH);
    float a0 = 0.f, a1 = 0.f, a2 = 0.f, a3 = 0.f;
#pragma unroll
    for (int j = 0; j < 16; ++j) {
        float4 e4 = er[j];
        a0 = fmaf(zrow[4 * j + 0], e4.x, a0);
        a1 = fmaf(zrow[4 * j + 1], e4.y, a1);
        a2 = fmaf(zrow[4 * j + 2], e4.z, a2);
        a3 = fmaf(zrow[4 * j + 3], e4.w, a3);
    }
    return enl[c] - 2.f * ((a0 + a1) + (a2 + a3));
}

// prep: blocks 0-3 enorm, block 4 col-stats + zero sums, 5-8 zero hist,
// 9-12 fp32->bf16 embedding table.
__global__ __launch_bounds__(256) void prep(const float* __restrict__ e,
                                            int* __restrict__ hist,
                                            float* __restrict__ sums,
                                            float* __restrict__ sum_zc,
                                            float* __restrict__ sum_ec,
                                            float* __restrict__ enorm,
                                            unsigned short* __restrict__ eb) {
    const int tid = threadIdx.x;
    const int bk = blockIdx.x;
    if (bk < 4) {
        int k = bk * 256 + tid;
        const float4* row = (const float4*)(e + (size_t)k * CH);
        float n = 0.f;
#pragma unroll
        for (int j = 0; j < CH / 4; ++j) {
            float4 v = row[j];
            n += v.x * v.x + v.y * v.y + v.z * v.z + v.w * v.w;
        }
        enorm[k] = n;
    } else if (bk == 4) {
        if (tid == 0) sums[0] = 0.f;
        if (tid < 64) sum_zc[tid] = 0.f;
        __shared__ float ls1[256];
        __shared__ float r2[4];
        int c = tid & 63;
        int strip = tid >> 6;
        float s1 = 0.f, s2 = 0.f;
        for (int k = strip * 256; k < strip * 256 + 256; ++k) {
            float v = e[k * CH + c];
            s1 += v;
            s2 = fmaf(v, v, s2);
        }
        ls1[tid] = s1;
        for (int off = 32; off; off >>= 1) s2 += __shfl_down(s2, off);
        if ((tid & 63) == 0) r2[tid >> 6] = s2;
        __syncthreads();
        if (strip == 0) sum_ec[c] = ls1[c] + ls1[64 + c] + ls1[128 + c] + ls1[192 + c];
        if (tid == 0) sums[1] = r2[0] + r2[1] + r2[2] + r2[3];
    } else if (bk < 9) {
        hist[(bk - 5) * 256 + tid] = 0;
    } else {
        int base = (bk - 9) * 16384;
        for (int j = 0; j < 64; ++j) {
            int i = base + tid + j * 256;
            eb[i] = f2bf(e[i]);
        }
    }
}

// A-fragment builder: 8 bf16 from zrow (channels base..base+7)
#define MK8(A, ptr)                                            \
    {                                                          \
        float4 _a = *(const float4*)(ptr);                     \
        float4 _b = *(const float4*)((ptr) + 4);               \
        A[0] = (short)f2bf(_a.x); A[1] = (short)f2bf(_a.y);    \
        A[2] = (short)f2bf(_a.z); A[3] = (short)f2bf(_a.w);    \
        A[4] = (short)f2bf(_b.x); A[5] = (short)f2bf(_b.y);    \
        A[6] = (short)f2bf(_b.z); A[7] = (short)f2bf(_b.w);    \
    }

// main: bf16-MFMA candidate generation with B-fragments read DIRECTLY from
// the L2-resident global bf16 table (no LDS staging, no per-chunk barriers),
// 32 tokens/wave for 2x B reuse. Exact fp32 rescore frozen.
// LDS = 39936 B -> 4 blocks/CU (16 waves). 3 __syncthreads total.
__global__ __launch_bounds__(256, 4) void vq_main(const float* __restrict__ z,
                                                  const float* __restrict__ emb,
                                                  const unsigned short* __restrict__ eb,
                                                  const float* __restrict__ enorm,
                                                  float* __restrict__ out,
                                                  int* __restrict__ hist,
                                                  float* __restrict__ sums,
                                                  float* __restrict__ sum_zc) {
    __shared__ float zl[MTOK * SZZ];          // 34816 B fp32 z, token-major
    __shared__ int   cand[MTOK][CAP];         // 4096 B (aliased as zs scratch at tail)
    __shared__ int   ccnt[MTOK];              // 512 B
    __shared__ int   fi[MTOK];                // 512 B

    const int tid = threadIdx.x;
    const int w = tid >> 6;             // wave 0..3
    const int lane = tid & 63;
    const int n15 = lane & 15;
    const int q = lane >> 4;            // 0..3
    const int t0 = blockIdx.x * MTOK;   // grid = 1024
    const int bb = t0 >> 15;
    const int s0 = t0 & (SP - 1);

    // ---- stage z tile token-major (fp32, needed exactly for rescore) ----
    {
        const float* zbase = z + ((size_t)bb * CH) * SP + s0;
#pragma unroll
        for (int rep = 0; rep < 8; ++rep) {
            int idx = tid + rep * 256;      // 0..2047
            int c = idx >> 5;
            int tq = idx & 31;
            float4 v = *(const float4*)(zbase + (size_t)c * SP + tq * 4);
            zl[(4 * tq + 0) * SZZ + c] = v.x;
            zl[(4 * tq + 1) * SZZ + c] = v.y;
            zl[(4 * tq + 2) * SZZ + c] = v.z;
            zl[(4 * tq + 3) * SZZ + c] = v.w;
        }
        if (tid < MTOK) ccnt[tid] = 0;
    }
    __syncthreads();

    // ---- persistent A fragments: 2 groups of 16 tokens per wave ----
    s16x8 A0, A1, A2, A3;
    {
        const float* zr0 = &zl[(w * 32 + n15) * SZZ];
        const float* zr1 = zr0 + 16 * SZZ;
        MK8(A0, zr0 + q * 8)
        MK8(A1, zr0 + 32 + q * 8)
        MK8(A2, zr1 + q * 8)
        MK8(A3, zr1 + 32 + q * 8)
    }

    // per-lane bases: B row = ct*16 + n15, cols q*8 / q*8+32; en same row
    const unsigned short* ebp = eb + (size_t)n15 * CH + q * 8;
    const float* enp = enorm + n15;

    // ---- pass 1: per-token min of d_bf (values only), barrier-free ----
    float bmin0[4] = {3.4e38f, 3.4e38f, 3.4e38f, 3.4e38f};
    float bmin1[4] = {3.4e38f, 3.4e38f, 3.4e38f, 3.4e38f};
#pragma unroll 4
    for (int ct = 0; ct < 64; ++ct) {
        const unsigned short* pr = ebp + (size_t)ct * (16 * CH);
        s16x8 B0 = *(const s16x8*)pr;
        s16x8 B1 = *(const s16x8*)(pr + 32);
        float en = enp[ct * 16];
        f32x4 acc0 = {0.f, 0.f, 0.f, 0.f};
        f32x4 acc1 = {0.f, 0.f, 0.f, 0.f};
        acc0 = __builtin_amdgcn_mfma_f32_16x16x32_bf16(A0, B0, acc0, 0, 0, 0);
        acc0 = __builtin_amdgcn_mfma_f32_16x16x32_bf16(A1, B1, acc0, 0, 0, 0);
        acc1 = __builtin_amdgcn_mfma_f32_16x16x32_bf16(A2, B0, acc1, 0, 0, 0);
        acc1 = __builtin_amdgcn_mfma_f32_16x16x32_bf16(A3, B1, acc1, 0, 0, 0);
#pragma unroll
        for (int r = 0; r < 4; ++r) {
            bmin0[r] = fminf(bmin0[r], fmaf(-2.f, acc0[r], en));
            bmin1[r] = fminf(bmin1[r], fmaf(-2.f, acc1[r], en));
        }
    }
    // butterfly over n15: leaves the min in ALL lanes of the group -> no LDS,
    // no barrier (threshold is consumed by the same wave that produced it)
#pragma unroll
    for (int off = 1; off < 16; off <<= 1)
#pragma unroll
        for (int r = 0; r < 4; ++r) {
            bmin0[r] = fminf(bmin0[r], __shfl_xor(bmin0[r], off));
            bmin1[r] = fminf(bmin1[r], __shfl_xor(bmin1[r], off));
        }
    float thr0[4], thr1[4];
#pragma unroll
    for (int r = 0; r < 4; ++r) {
        thr0[r] = bmin0[r] + MARGIN;
        thr1[r] = bmin1[r] + MARGIN;
    }

    // ---- pass 2: identical compute, collect candidates within margin ----
    const int tb0 = w * 32 + 4 * q;      // group-0 tokens: tb0 + r
    const int tb1 = tb0 + 16;            // group-1 tokens
#pragma unroll 4
    for (int ct = 0; ct < 64; ++ct) {
        const unsigned short* pr = ebp + (size_t)ct * (16 * CH);
        s16x8 B0 = *(const s16x8*)pr;
        s16x8 B1 = *(const s16x8*)(pr + 32);
        float en = enp[ct * 16];
        f32x4 acc0 = {0.f, 0.f, 0.f, 0.f};
        f32x4 acc1 = {0.f, 0.f, 0.f, 0.f};
        acc0 = __builtin_amdgcn_mfma_f32_16x16x32_bf16(A0, B0, acc0, 0, 0, 0);
        acc0 = __builtin_amdgcn_mfma_f32_16x16x32_bf16(A1, B1, acc0, 0, 0, 0);
        acc1 = __builtin_amdgcn_mfma_f32_16x16x32_bf16(A2, B0, acc1, 0, 0, 0);
        acc1 = __builtin_amdgcn_mfma_f32_16x16x32_bf16(A3, B1, acc1, 0, 0, 0);
        int code = ct * 16 + n15;
#pragma unroll
        for (int r = 0; r < 4; ++r) {
            float d0 = fmaf(-2.f, acc0[r], en);
            if (d0 <= thr0[r]) {
                int pos = atomicAdd(&ccnt[tb0 + r], 1);
                if (pos < CAP) cand[tb0 + r][pos] = code;
            }
            float d1 = fmaf(-2.f, acc1[r], en);
            if (d1 <= thr1[r]) {
                int pos = atomicAdd(&ccnt[tb1 + r], 1);
                if (pos < CAP) cand[tb1 + r][pos] = code;
            }
        }
    }
    __syncthreads();

    // ---- exact fp32 rescore of candidates (frozen arithmetic) ----
    if (tid < MTOK) {
        int t = tid;
        const float* zrow = &zl[t * SZZ];
        int cnt = ccnt[t];
        float best = 3.4e38f;
        int bi = 0;
        if (cnt <= CAP) {
            for (int j = 0; j < cnt; ++j) {
                int c = cand[t][j];
                float d = exact_dist(zrow, emb, enorm, c);
                if (d < best || (d == best && c < bi)) { best = d; bi = c; }
            }
        } else {   // overflow fallback (provably ~never): exact scan, ascending
            for (int c = 0; c < KC; ++c) {
                float d = exact_dist(zrow, emb, enorm, c);
                if (d < best) { best = d; bi = c; }
            }
        }
        fi[t] = bi;
        out[OFF_IDX + t0 + t] = (float)bi;   // coalesced
        atomicAdd(&hist[bi], 1);
    }
    __syncthreads();

    // ---- z_q epilogue: z + (e[code] - z), coalesced per channel ----
#pragma unroll
    for (int rep = 0; rep < 32; ++rep) {
        int idx = tid + rep * 256;   // 0..8191
        int c = idx >> 7;
        int t = idx & 127;
        int code = fi[t];
        float ev = emb[(size_t)code * CH + c];   // L1/L2-hot gather (row shared by 2 threads)
        float zv = zl[t * SZZ + c];
        out[OFF_ZQ + ((size_t)bb * CH + c) * SP + s0 + t] = zv + (ev - zv);
    }

    // ---- z statistics at tail: two 64-token halves, partial sums bitwise
    //      identical to the previous per-64-token-block grouping ----
    float* zs = reinterpret_cast<float*>(cand);   // 2048 B needed <= 4096 B
#pragma unroll
    for (int h = 0; h < 2; ++h) {
        const int c = tid >> 2, qq = tid & 3;
        float s1 = 0.f, s2 = 0.f;
#pragma unroll
        for (int tt = 0; tt < 16; ++tt) {
            float v = zl[(h * 64 + qq * 16 + tt) * SZZ + c];
            s1 += v;
            s2 = fmaf(v, v, s2);
        }
        zs[tid] = s1;
        zs[256 + tid] = s2;
        __syncthreads();
        if (tid < 64) {
            float a = zs[4 * tid] + zs[4 * tid + 1] + zs[4 * tid + 2] + zs[4 * tid + 3];
            atomicAdd(&sum_zc[tid], a);
            float bsum = zs[256 + 4 * tid] + zs[256 + 4 * tid + 1]
                       + zs[256 + 4 * tid + 2] + zs[256 + 4 * tid + 3];
            for (int off = 32; off; off >>= 1) bsum += __shfl_down(bsum, off);
            if (tid == 0) atomicAdd(&sums[0], bsum);
        }
        __syncthreads();
    }
}

__global__ __launch_bounds__(1024) void finalize(const int* __restrict__ hist,
                                                 const float* __restrict__ sums,
                                                 const float* __restrict__ sum_zc,
                                                 const float* __restrict__ sum_ec,
                                                 float* __restrict__ out) {
    __shared__ float red[1024];
    int k = threadIdx.x;
    float p = (float)hist[k] * (1.0f / (float)NTOK);
    red[k] = p * logf(p + 1e-10f);
    __syncthreads();
    for (int off = 512; off; off >>= 1) {
        if (k < off) red[k] += red[k + off];
        __syncthreads();
    }
    if (k == 0) {
        out[OFF_PERP] = expf(-red[0]);
        out[OFF_LOSS] = 0.f;
        double dot = 0.0;
        for (int c = 0; c < CH; ++c) dot += (double)sum_zc[c] * (double)sum_ec[c];
        double mean = ((double)KC * (double)sums[0] + (double)NTOK * (double)sums[1] - 2.0 * dot)
                      / ((double)NTOK * (double)KC);
        out[OFF_MEAN] = (float)mean;
    }
}

extern "C" void kernel_launch(void* const* d_in, const int* in_sizes, int n_in,
                              void* d_out, int out_size, void* d_ws, size_t ws_size,
                              hipStream_t stream) {
    const float* z   = (const float*)d_in[0];
    const float* emb = (const float*)d_in[1];
    float* out = (float*)d_out;

    int*            hist   = (int*)d_ws;
    float*          sums   = (float*)d_ws + 1024;   // [0]=sum_z2 [1]=sum_e2
    float*          sum_zc = (float*)d_ws + 1026;
    float*          sum_ec = (float*)d_ws + 1090;
    float*          enorm  = (float*)d_ws + 1154;
    unsigned short* eb     = (unsigned short*)((int*)d_ws + 4096);  // 128 KB bf16 table

    prep<<<13, 256, 0, stream>>>(emb, hist, sums, sum_zc, sum_ec, enorm, eb);
    vq_main<<<NTOK / MTOK, 256, 0, stream>>>(z, emb, eb, enorm, out, hist, sums, sum_zc);
    finalize<<<1, 1024, 0, stream>>>(hist, sums, sum_zc, sum_ec, out);
}